// Round 5
// baseline (303.568 us; speedup 1.0000x reference)
//
#include <hip/hip_runtime.h>
#include <hip/hip_bf16.h>

#define S_LEN 2048
#define DM 1024
#define NH 16
#define DH 64
#define MROWS 4096  // B*S

typedef __hip_bfloat16 hbf;
typedef __attribute__((ext_vector_type(4))) float floatx4;
typedef __bf16 bf16x8 __attribute__((ext_vector_type(8)));

#define QSCALE 0.18033688f   // 0.125 * log2(e)  (score in log2 domain)
#define EXP_BIAS 5.77078016f // 4 * log2(e)

// async global->LDS 16B/lane (dest must be wave-uniform base + lane*16)
__device__ __forceinline__ void gload_lds16(const void* g, void* l) {
  __builtin_amdgcn_global_load_lds(
      (const __attribute__((address_space(1))) unsigned int*)g,
      (__attribute__((address_space(3))) unsigned int*)l, 16, 0, 0);
}

// ---------------- 1. fused: fp32->bf16 convert (q,k,v) + weight transpose ----------------
__global__ __launch_bounds__(256) void cvt3w(
    const float* __restrict__ q, const float* __restrict__ k, const float* __restrict__ v,
    hbf* __restrict__ Xq, hbf* __restrict__ Xk, hbf* __restrict__ Xv,
    const float* __restrict__ wq, const float* __restrict__ wk,
    const float* __restrict__ wv, const float* __restrict__ wo,
    hbf* __restrict__ Wqt, hbf* __restrict__ Wkt,
    hbf* __restrict__ Wvt, hbf* __restrict__ Wot) {
  __shared__ float tile[64][65];
  if (blockIdx.y < 3) {
    const float* src; hbf* dst;
    switch (blockIdx.y) {
      case 0:  src = q; dst = Xq; break;
      case 1:  src = k; dst = Xk; break;
      default: src = v; dst = Xv; break;
    }
    int i = blockIdx.x * 256 + threadIdx.x;
    float4 val = ((const float4*)src)[i];
    union { hbf h[4]; uint2 u; } pk;
    pk.h[0] = __float2bfloat16(val.x);
    pk.h[1] = __float2bfloat16(val.y);
    pk.h[2] = __float2bfloat16(val.z);
    pk.h[3] = __float2bfloat16(val.w);
    ((uint2*)dst)[i] = pk.u;
    return;
  }
  // weight transpose: 1024 blocks needed
  if (blockIdx.x >= 1024) return;
  const float* W; hbf* Wt;
  switch (blockIdx.x >> 8) {
    case 0:  W = wq; Wt = Wqt; break;
    case 1:  W = wk; Wt = Wkt; break;
    case 2:  W = wv; Wt = Wvt; break;
    default: W = wo; Wt = Wot; break;
  }
  const int t8 = blockIdx.x & 255;
  const int n0 = (t8 & 15) * 64, k0 = (t8 >> 4) * 64;
  const int t = threadIdx.x;
  const int col = t & 63, rb = t >> 6;
#pragma unroll
  for (int i = 0; i < 16; ++i) {
    int row = i * 4 + rb;
    tile[row][col] = W[(size_t)(k0 + row) * DM + n0 + col];
  }
  __syncthreads();
#pragma unroll
  for (int i = 0; i < 16; ++i) {
    int row = i * 4 + rb;  // n-local
    Wt[(size_t)(n0 + row) * DM + k0 + col] = __float2bfloat16(tile[col][row]);
  }
}

// ---------------- 2. QKV projection GEMM (128x128, BK=32, m97 structure) ----------------
// Q: scaled by QSCALE, head-split (B,H,S,64). K: head-split. V: written TRANSPOSED (B,H,64,S).
__global__ __launch_bounds__(256) void gemm_qkv(
    const hbf* __restrict__ Xq, const hbf* __restrict__ Xk, const hbf* __restrict__ Xv,
    const hbf* __restrict__ Wqt, const hbf* __restrict__ Wkt, const hbf* __restrict__ Wvt,
    const float* __restrict__ bq, const float* __restrict__ bk, const float* __restrict__ bv,
    hbf* __restrict__ Qh, hbf* __restrict__ Kh, hbf* __restrict__ Vt) {
  const hbf* A; const hbf* Wt; const float* bias; hbf* Out; float oscale;
  const int z = blockIdx.z;
  if (z == 0)      { A = Xq; Wt = Wqt; bias = bq; Out = Qh; oscale = QSCALE; }
  else if (z == 1) { A = Xk; Wt = Wkt; bias = bk; Out = Kh; oscale = 1.0f; }
  else             { A = Xv; Wt = Wvt; bias = bv; Out = Vt; oscale = 1.0f; }

  __shared__ __align__(16) hbf As[128 * 32];
  __shared__ __align__(16) hbf Bs[128 * 32];

  const int tid = threadIdx.x;
  const int lane = tid & 63, wave = tid >> 6;
  const int l15 = lane & 15, quad = lane >> 4;
  const int wm = wave >> 1, wn = wave & 1;
  const int m0 = blockIdx.x * 128, n0 = blockIdx.y * 128;

  floatx4 acc[4][4] = {};

#pragma unroll 1
  for (int k0 = 0; k0 < DM; k0 += 32) {
#pragma unroll
    for (int it = 0; it < 2; ++it) {
      int c = tid + it * 256;
      int row = c >> 2, cc = (c & 3) << 3;
      gload_lds16(&A[(size_t)(m0 + row) * DM + k0 + cc], &As[row * 32 + cc]);
      gload_lds16(&Wt[(size_t)(n0 + row) * DM + k0 + cc], &Bs[row * 32 + cc]);
    }
    __syncthreads();
    bf16x8 af[4], bfr[4];
#pragma unroll
    for (int mi = 0; mi < 4; ++mi)
      af[mi] = *(const bf16x8*)&As[(wm * 64 + mi * 16 + l15) * 32 + quad * 8];
#pragma unroll
    for (int ni = 0; ni < 4; ++ni)
      bfr[ni] = *(const bf16x8*)&Bs[(wn * 64 + ni * 16 + l15) * 32 + quad * 8];
#pragma unroll
    for (int mi = 0; mi < 4; ++mi)
#pragma unroll
      for (int ni = 0; ni < 4; ++ni)
        acc[mi][ni] = __builtin_amdgcn_mfma_f32_16x16x32_bf16(af[mi], bfr[ni], acc[mi][ni], 0, 0, 0);
    __syncthreads();
  }

#pragma unroll
  for (int mi = 0; mi < 4; ++mi) {
#pragma unroll
    for (int ni = 0; ni < 4; ++ni) {
      int col = n0 + wn * 64 + ni * 16 + l15;
      float bb_ = bias[col];
#pragma unroll
      for (int r = 0; r < 4; ++r) {
        int row = m0 + wm * 64 + mi * 16 + quad * 4 + r;
        float vv = (acc[mi][ni][r] + bb_) * oscale;
        int b = row >> 11, s = row & 2047, h = col >> 6, dd = col & 63;
        size_t idx;
        if (z == 2)  // V transposed: (B,H,64,S)
          idx = ((((size_t)b * NH + h) * DH + dd) * S_LEN) + s;
        else         // (B,H,S,64)
          idx = ((((size_t)b * NH + h) * S_LEN + s) << 6) + dd;
        Out[idx] = __float2bfloat16(vv);
      }
    }
  }
}

// ---------------- 3. flash attention v5: XCD-swizzled, pipelined, split-K ----------------
// 1-D grid of 1024; XCD j (= id%8) only handles bh in [4j, 4j+4) -> 2 MB K/V
// working set per XCD (fits 4 MB L2). K and V both prefetched one 32-key tile
// ahead (overwrite-in-place after last use). Fixed-max softmax in log2 domain.
__global__ __launch_bounds__(256, 4) void flash_attn(
    const hbf* __restrict__ Qh, const hbf* __restrict__ Kh,
    const hbf* __restrict__ Vt, hbf* __restrict__ AO) {
  const int id = blockIdx.x;
  const int bh = (id & 7) * 4 + (id >> 8);     // XCD-local bh group
  const int q0 = ((id >> 3) & 31) * 64;
  const int b = bh >> 4, h = bh & 15;
  const int tid = threadIdx.x;
  const int lane = tid & 63, wave = tid >> 6;
  const int qw = wave & 1;       // q-half within block
  const int ksplit = wave >> 1;  // key half
  const int l15 = lane & 15, quad = lane >> 4;

  // per-wave P tile (32x40 bf16 = 2560B, x4) overlaid by combine Obuf (2x32x68 fp32)
  __shared__ __align__(16) unsigned char smem[17408];
  __shared__ float Lbuf[2][32];
  hbf* Pw = (hbf*)(smem + wave * 2560);

  const size_t qbase = (((size_t)bh) * S_LEN + q0 + qw * 32) * DH;
  bf16x8 qf[2][2];
#pragma unroll
  for (int mi = 0; mi < 2; ++mi)
#pragma unroll
    for (int ks = 0; ks < 2; ++ks)
      qf[mi][ks] = *(const bf16x8*)&Qh[qbase + (size_t)(mi * 16 + l15) * DH + ks * 32 + quad * 8];

  // ones B-fragment: B[k][0]=1 -> lsum col 0 = row-sum
  bf16x8 ones_f;
  {
    const __bf16 ov = (l15 == 0) ? (__bf16)1.0f : (__bf16)0.0f;
#pragma unroll
    for (int j = 0; j < 8; ++j) ones_f[j] = ov;
  }

  floatx4 o[2][4] = {};
  floatx4 lsum[2] = {};

  const hbf* Kb = Kh + ((size_t)bh) * S_LEN * DH;
  const hbf* Vb = Vt + ((size_t)bh) * DH * S_LEN;
  const int kstart = ksplit * (S_LEN / 2);

  // preload K and V fragments for tile 0
  bf16x8 kf[2][2], vf[4];
#pragma unroll
  for (int ni = 0; ni < 2; ++ni)
#pragma unroll
    for (int ks = 0; ks < 2; ++ks)
      kf[ni][ks] = *(const bf16x8*)&Kb[(size_t)(kstart + ni * 16 + l15) * DH + ks * 32 + quad * 8];
#pragma unroll
  for (int nd = 0; nd < 4; ++nd)
    vf[nd] = *(const bf16x8*)&Vb[(size_t)(nd * 16 + l15) * S_LEN + kstart + quad * 8];

#pragma unroll 1
  for (int it = 0; it < 32; ++it) {
    const int k0 = kstart + it * 32;
    const int kn = (it == 31) ? kstart : k0 + 32;

    // S = Q K^T on prefetched K frags
    floatx4 sacc[2][2] = {};
#pragma unroll
    for (int ks = 0; ks < 2; ++ks)
#pragma unroll
      for (int mi = 0; mi < 2; ++mi)
#pragma unroll
        for (int ni = 0; ni < 2; ++ni)
          sacc[mi][ni] = __builtin_amdgcn_mfma_f32_16x16x32_bf16(qf[mi][ks], kf[ni][ks], sacc[mi][ni], 0, 0, 0);

    // prefetch next-tile K (overwrite: old value dead after QK)
#pragma unroll
    for (int ni = 0; ni < 2; ++ni)
#pragma unroll
      for (int ks = 0; ks < 2; ++ks)
        kf[ni][ks] = *(const bf16x8*)&Kb[(size_t)(kn + ni * 16 + l15) * DH + ks * 32 + quad * 8];

    // p = exp2(s - EXP_BIAS), store to per-wave LDS (same-wave RAW only)
#pragma unroll
    for (int mi = 0; mi < 2; ++mi)
#pragma unroll
      for (int ni = 0; ni < 2; ++ni)
#pragma unroll
        for (int r = 0; r < 4; ++r) {
          float p = exp2f(sacc[mi][ni][r] - EXP_BIAS);
          Pw[(mi * 16 + quad * 4 + r) * 40 + ni * 16 + l15] = __float2bfloat16(p);
        }

    // read P back in A-layout
    bf16x8 pf[2];
#pragma unroll
    for (int mi = 0; mi < 2; ++mi)
      pf[mi] = *(const bf16x8*)&Pw[(mi * 16 + l15) * 40 + quad * 8];

    // row-sums via ones-MFMA
#pragma unroll
    for (int mi = 0; mi < 2; ++mi)
      lsum[mi] = __builtin_amdgcn_mfma_f32_16x16x32_bf16(pf[mi], ones_f, lsum[mi], 0, 0, 0);

    // O += P V on this tile's V frags
#pragma unroll
    for (int nd = 0; nd < 4; ++nd)
#pragma unroll
      for (int mi = 0; mi < 2; ++mi)
        o[mi][nd] = __builtin_amdgcn_mfma_f32_16x16x32_bf16(pf[mi], vf[nd], o[mi][nd], 0, 0, 0);

    // prefetch next-tile V (overwrite: old value dead after PV)
#pragma unroll
    for (int nd = 0; nd < 4; ++nd)
      vf[nd] = *(const bf16x8*)&Vb[(size_t)(nd * 16 + l15) * S_LEN + kn + quad * 8];
  }

  // ---- split-K combine via LDS ----
  __syncthreads();  // all waves done with Pw before reuse as Obuf
  if (ksplit == 1) {
    float* Ob = (float*)smem + qw * (32 * 68);
#pragma unroll
    for (int mi = 0; mi < 2; ++mi)
#pragma unroll
      for (int nd = 0; nd < 4; ++nd)
#pragma unroll
        for (int r = 0; r < 4; ++r)
          Ob[(mi * 16 + quad * 4 + r) * 68 + nd * 16 + l15] = o[mi][nd][r];
    if (l15 == 0) {
#pragma unroll
      for (int mi = 0; mi < 2; ++mi)
#pragma unroll
        for (int r = 0; r < 4; ++r)
          Lbuf[qw][mi * 16 + quad * 4 + r] = lsum[mi][r];
    }
  }
  __syncthreads();
  if (ksplit == 0) {
    const float* Ob = (const float*)smem + qw * (32 * 68);
#pragma unroll
    for (int mi = 0; mi < 2; ++mi) {
      float linv[4];
#pragma unroll
      for (int r = 0; r < 4; ++r) {
        float lq = __shfl(lsum[mi][r], lane & 48, 64) + Lbuf[qw][mi * 16 + quad * 4 + r];
        linv[r] = 1.0f / lq;
      }
#pragma unroll
      for (int nd = 0; nd < 4; ++nd) {
#pragma unroll
        for (int r = 0; r < 4; ++r) {
          int rl = mi * 16 + quad * 4 + r;
          int qrow = q0 + qw * 32 + rl;
          int dd = nd * 16 + l15;
          float vv = (o[mi][nd][r] + Ob[rl * 68 + dd]) * linv[r];
          AO[(((size_t)b * S_LEN + qrow) << 10) + h * DH + dd] = __float2bfloat16(vv);
        }
      }
    }
  }
}

// ---------------- 4. output projection GEMM (128x64, BK=32) -> fp32 ----------------
__global__ __launch_bounds__(256) void gemm_out(
    const hbf* __restrict__ A, const hbf* __restrict__ Wt,
    const float* __restrict__ bias, float* __restrict__ Out) {
  __shared__ __align__(16) hbf As[128 * 32];
  __shared__ __align__(16) hbf Bs[64 * 32];

  const int tid = threadIdx.x;
  const int lane = tid & 63, wave = tid >> 6;
  const int l15 = lane & 15, quad = lane >> 4;
  const int wm = wave >> 1, wn = wave & 1;
  const int m0 = blockIdx.x * 128, n0 = blockIdx.y * 64;

  floatx4 acc[4][2] = {};

#pragma unroll 1
  for (int k0 = 0; k0 < DM; k0 += 32) {
#pragma unroll
    for (int it = 0; it < 2; ++it) {
      int c = tid + it * 256;
      int row = c >> 2, cc = (c & 3) << 3;
      gload_lds16(&A[(size_t)(m0 + row) * DM + k0 + cc], &As[row * 32 + cc]);
    }
    {
      int row = tid >> 2, cc = (tid & 3) << 3;
      gload_lds16(&Wt[(size_t)(n0 + row) * DM + k0 + cc], &Bs[row * 32 + cc]);
    }
    __syncthreads();
    bf16x8 af[4], bfr[2];
#pragma unroll
    for (int mi = 0; mi < 4; ++mi)
      af[mi] = *(const bf16x8*)&As[(wm * 64 + mi * 16 + l15) * 32 + quad * 8];
#pragma unroll
    for (int ni = 0; ni < 2; ++ni)
      bfr[ni] = *(const bf16x8*)&Bs[(wn * 32 + ni * 16 + l15) * 32 + quad * 8];
#pragma unroll
    for (int mi = 0; mi < 4; ++mi)
#pragma unroll
      for (int ni = 0; ni < 2; ++ni)
        acc[mi][ni] = __builtin_amdgcn_mfma_f32_16x16x32_bf16(af[mi], bfr[ni], acc[mi][ni], 0, 0, 0);
    __syncthreads();
  }

#pragma unroll
  for (int mi = 0; mi < 4; ++mi) {
#pragma unroll
    for (int ni = 0; ni < 2; ++ni) {
      int col = n0 + wn * 32 + ni * 16 + l15;
      float bb_ = bias[col];
#pragma unroll
      for (int r = 0; r < 4; ++r) {
        int row = m0 + wm * 64 + mi * 16 + quad * 4 + r;
        Out[(size_t)row * DM + col] = acc[mi][ni][r] + bb_;
      }
    }
  }
}

// ---------------- launch ----------------
extern "C" void kernel_launch(void* const* d_in, const int* in_sizes, int n_in,
                              void* d_out, int out_size, void* d_ws, size_t ws_size,
                              hipStream_t stream) {
  const float* v  = (const float*)d_in[0];
  const float* k  = (const float*)d_in[1];
  const float* q  = (const float*)d_in[2];
  const float* wq = (const float*)d_in[3];
  const float* bq = (const float*)d_in[4];
  const float* wk = (const float*)d_in[5];
  const float* bk = (const float*)d_in[6];
  const float* wv = (const float*)d_in[7];
  const float* bv = (const float*)d_in[8];
  const float* wo = (const float*)d_in[9];
  const float* bo = (const float*)d_in[10];

  const size_t NX = (size_t)MROWS * DM;  // 4M elems
  const size_t NW = (size_t)DM * DM;     // 1M elems
  hbf* base = (hbf*)d_ws;
  hbf* Xq  = base;
  hbf* Xk  = Xq + NX;
  hbf* Xv  = Xk + NX;
  hbf* Wqt = Xv + NX;
  hbf* Wkt = Wqt + NW;
  hbf* Wvt = Wkt + NW;
  hbf* Wot = Wvt + NW;
  hbf* Qh  = Wot + NW;
  hbf* Kh  = Qh + NX;
  hbf* Vtr = Kh + NX;
  hbf* AO  = Vtr + NX;

  cvt3w<<<dim3(4096, 4), 256, 0, stream>>>(q, k, v, Xq, Xk, Xv,
                                           wq, wk, wv, wo, Wqt, Wkt, Wvt, Wot);
  gemm_qkv<<<dim3(32, 8, 3), 256, 0, stream>>>(Xq, Xk, Xv, Wqt, Wkt, Wvt, bq, bk, bv, Qh, Kh, Vtr);
  flash_attn<<<1024, 256, 0, stream>>>(Qh, Kh, Vtr, AO);
  gemm_out<<<dim3(32, 16), 256, 0, stream>>>(AO, Wot, bo, (float*)d_out);
}

// Round 6
// 254.461 us; speedup vs baseline: 1.1930x; 1.1930x over previous
//
#include <hip/hip_runtime.h>
#include <hip/hip_bf16.h>

#define S_LEN 2048
#define DM 1024
#define NH 16
#define DH 64
#define MROWS 4096  // B*S

typedef __hip_bfloat16 hbf;
typedef __attribute__((ext_vector_type(4))) float floatx4;
typedef __bf16 bf16x8 __attribute__((ext_vector_type(8)));

#define QSCALE 0.18033688f   // 0.125 * log2(e)  (score in log2 domain)
#define EXP_BIAS 5.77078016f // 4 * log2(e)

// async global->LDS 16B/lane (dest must be wave-uniform base + lane*16)
__device__ __forceinline__ void gload_lds16(const void* g, void* l) {
  __builtin_amdgcn_global_load_lds(
      (const __attribute__((address_space(1))) unsigned int*)g,
      (__attribute__((address_space(3))) unsigned int*)l, 16, 0, 0);
}

// ---------------- 1. fused: fp32->bf16 convert (q,k,v) + weight transpose ----------------
__global__ __launch_bounds__(256) void cvt3w(
    const float* __restrict__ q, const float* __restrict__ k, const float* __restrict__ v,
    hbf* __restrict__ Xq, hbf* __restrict__ Xk, hbf* __restrict__ Xv,
    const float* __restrict__ wq, const float* __restrict__ wk,
    const float* __restrict__ wv, const float* __restrict__ wo,
    hbf* __restrict__ Wqt, hbf* __restrict__ Wkt,
    hbf* __restrict__ Wvt, hbf* __restrict__ Wot) {
  __shared__ float tile[64][65];
  if (blockIdx.y < 3) {
    const float* src; hbf* dst;
    switch (blockIdx.y) {
      case 0:  src = q; dst = Xq; break;
      case 1:  src = k; dst = Xk; break;
      default: src = v; dst = Xv; break;
    }
    int i = blockIdx.x * 256 + threadIdx.x;
    float4 val = ((const float4*)src)[i];
    union { hbf h[4]; uint2 u; } pk;
    pk.h[0] = __float2bfloat16(val.x);
    pk.h[1] = __float2bfloat16(val.y);
    pk.h[2] = __float2bfloat16(val.z);
    pk.h[3] = __float2bfloat16(val.w);
    ((uint2*)dst)[i] = pk.u;
    return;
  }
  // weight transpose: 1024 blocks needed
  if (blockIdx.x >= 1024) return;
  const float* W; hbf* Wt;
  switch (blockIdx.x >> 8) {
    case 0:  W = wq; Wt = Wqt; break;
    case 1:  W = wk; Wt = Wkt; break;
    case 2:  W = wv; Wt = Wvt; break;
    default: W = wo; Wt = Wot; break;
  }
  const int t8 = blockIdx.x & 255;
  const int n0 = (t8 & 15) * 64, k0 = (t8 >> 4) * 64;
  const int t = threadIdx.x;
  const int col = t & 63, rb = t >> 6;
#pragma unroll
  for (int i = 0; i < 16; ++i) {
    int row = i * 4 + rb;
    tile[row][col] = W[(size_t)(k0 + row) * DM + n0 + col];
  }
  __syncthreads();
#pragma unroll
  for (int i = 0; i < 16; ++i) {
    int row = i * 4 + rb;  // n-local
    Wt[(size_t)(n0 + row) * DM + k0 + col] = __float2bfloat16(tile[col][row]);
  }
}

// ---------------- 2. QKV projection GEMM (128x128, BK=32) ----------------
// Q: scaled by QSCALE, head-split (B,H,S,64).
// K,V: written in FRAGMENT-LINEAR layout: per (bh, 32-key tile kt), 4 fragments
// of 1KB; byte addr = ((bh*64+kt)*4 + frag)*1024 + lane*16. Flash reads these
// as fully-coalesced 1KB streams (fixes 16-way L1 set thrash of strided V).
__global__ __launch_bounds__(256) void gemm_qkv(
    const hbf* __restrict__ Xq, const hbf* __restrict__ Xk, const hbf* __restrict__ Xv,
    const hbf* __restrict__ Wqt, const hbf* __restrict__ Wkt, const hbf* __restrict__ Wvt,
    const float* __restrict__ bq, const float* __restrict__ bk, const float* __restrict__ bv,
    hbf* __restrict__ Qh, hbf* __restrict__ Kf, hbf* __restrict__ Vf) {
  const hbf* A; const hbf* Wt; const float* bias; hbf* Out; float oscale;
  const int z = blockIdx.z;
  if (z == 0)      { A = Xq; Wt = Wqt; bias = bq; Out = Qh; oscale = QSCALE; }
  else if (z == 1) { A = Xk; Wt = Wkt; bias = bk; Out = Kf; oscale = 1.0f; }
  else             { A = Xv; Wt = Wvt; bias = bv; Out = Vf; oscale = 1.0f; }

  __shared__ __align__(16) hbf As[128 * 32];
  __shared__ __align__(16) hbf Bs[128 * 32];

  const int tid = threadIdx.x;
  const int lane = tid & 63, wave = tid >> 6;
  const int l15 = lane & 15, quad = lane >> 4;
  const int wm = wave >> 1, wn = wave & 1;
  const int m0 = blockIdx.x * 128, n0 = blockIdx.y * 128;

  floatx4 acc[4][4] = {};

#pragma unroll 1
  for (int k0 = 0; k0 < DM; k0 += 32) {
#pragma unroll
    for (int it = 0; it < 2; ++it) {
      int c = tid + it * 256;
      int row = c >> 2, cc = (c & 3) << 3;
      gload_lds16(&A[(size_t)(m0 + row) * DM + k0 + cc], &As[row * 32 + cc]);
      gload_lds16(&Wt[(size_t)(n0 + row) * DM + k0 + cc], &Bs[row * 32 + cc]);
    }
    __syncthreads();
    bf16x8 af[4], bfr[4];
#pragma unroll
    for (int mi = 0; mi < 4; ++mi)
      af[mi] = *(const bf16x8*)&As[(wm * 64 + mi * 16 + l15) * 32 + quad * 8];
#pragma unroll
    for (int ni = 0; ni < 4; ++ni)
      bfr[ni] = *(const bf16x8*)&Bs[(wn * 64 + ni * 16 + l15) * 32 + quad * 8];
#pragma unroll
    for (int mi = 0; mi < 4; ++mi)
#pragma unroll
      for (int ni = 0; ni < 4; ++ni)
        acc[mi][ni] = __builtin_amdgcn_mfma_f32_16x16x32_bf16(af[mi], bfr[ni], acc[mi][ni], 0, 0, 0);
    __syncthreads();
  }

#pragma unroll
  for (int mi = 0; mi < 4; ++mi) {
#pragma unroll
    for (int ni = 0; ni < 4; ++ni) {
      int col = n0 + wn * 64 + ni * 16 + l15;
      float bb_ = bias[col];
#pragma unroll
      for (int r = 0; r < 4; ++r) {
        int row = m0 + wm * 64 + mi * 16 + quad * 4 + r;
        float vv = (acc[mi][ni][r] + bb_) * oscale;
        int b = row >> 11, s = row & 2047, h = col >> 6, dd = col & 63;
        int bh = b * NH + h;
        size_t idx;
        if (z == 1) {
          // K-hat: element K[key=s][dim=dd]
          int kt = s >> 5, nif = (s >> 4) & 1, fl15 = s & 15;
          int ksf = dd >> 5, fquad = (dd >> 3) & 3, e = dd & 7;
          idx = (((size_t)bh * 64 + kt) * 4 + ksf * 2 + nif) * 512 + (fquad * 16 + fl15) * 8 + e;
        } else if (z == 2) {
          // V-hat: element V[key=s][dim=dd]
          int kt = s >> 5, fquad = (s >> 3) & 3, e = s & 7;
          int nd = dd >> 4, fl15 = dd & 15;
          idx = (((size_t)bh * 64 + kt) * 4 + nd) * 512 + (fquad * 16 + fl15) * 8 + e;
        } else {
          // Q: (B,H,S,64)
          idx = (((size_t)bh * S_LEN + s) << 6) + dd;
        }
        Out[idx] = __float2bfloat16(vv);
      }
    }
  }
}

// ---------------- 3. flash attention v6: fragment-linear K/V, XCD-swizzled ----------------
// 1-D grid of 1024; XCD j (= id%8) handles bh in [4j, 4j+4) -> 2 MB K/V per-XCD
// L2 working set. K/V fragment loads are contiguous 1KB (base + lane*16).
// K and V prefetched one 32-key tile ahead. Fixed-max softmax in log2 domain.
__global__ __launch_bounds__(256, 4) void flash_attn(
    const hbf* __restrict__ Qh, const hbf* __restrict__ Kf,
    const hbf* __restrict__ Vf, hbf* __restrict__ AO) {
  const int id = blockIdx.x;
  const int bh = (id & 7) * 4 + (id >> 8);     // XCD-local bh group
  const int q0 = ((id >> 3) & 31) * 64;
  const int b = bh >> 4, h = bh & 15;
  const int tid = threadIdx.x;
  const int lane = tid & 63, wave = tid >> 6;
  const int qw = wave & 1;       // q-half within block
  const int ksplit = wave >> 1;  // key half
  const int l15 = lane & 15, quad = lane >> 4;

  // per-wave P tile (32x40 bf16 = 2560B, x4) overlaid by combine Obuf (2x32x68 fp32)
  __shared__ __align__(16) unsigned char smem[17408];
  __shared__ float Lbuf[2][32];
  hbf* Pw = (hbf*)(smem + wave * 2560);

  const size_t qbase = (((size_t)bh) * S_LEN + q0 + qw * 32) * DH;
  bf16x8 qf[2][2];
#pragma unroll
  for (int mi = 0; mi < 2; ++mi)
#pragma unroll
    for (int ks = 0; ks < 2; ++ks)
      qf[mi][ks] = *(const bf16x8*)&Qh[qbase + (size_t)(mi * 16 + l15) * DH + ks * 32 + quad * 8];

  // ones B-fragment: B[k][0]=1 -> lsum col 0 = row-sum
  bf16x8 ones_f;
  {
    const __bf16 ov = (l15 == 0) ? (__bf16)1.0f : (__bf16)0.0f;
#pragma unroll
    for (int j = 0; j < 8; ++j) ones_f[j] = ov;
  }

  floatx4 o[2][4] = {};
  floatx4 lsum[2] = {};

  // fragment-linear bases for this wave's key half (32 tiles of 2048 elems each)
  const hbf* Kb = Kf + ((size_t)bh * 64 + ksplit * 32) * 2048 + lane * 8;
  const hbf* Vb = Vf + ((size_t)bh * 64 + ksplit * 32) * 2048 + lane * 8;

  // preload K and V fragments for tile 0
  bf16x8 kf[2][2], vf[4];
#pragma unroll
  for (int ni = 0; ni < 2; ++ni)
#pragma unroll
    for (int ks = 0; ks < 2; ++ks)
      kf[ni][ks] = *(const bf16x8*)&Kb[(ks * 2 + ni) * 512];
#pragma unroll
  for (int nd = 0; nd < 4; ++nd)
    vf[nd] = *(const bf16x8*)&Vb[nd * 512];

#pragma unroll 1
  for (int it = 0; it < 32; ++it) {
    const int tn = (it == 31) ? 0 : (it + 1) * 2048;  // next tile offset (elems)

    // S = Q K^T on prefetched K frags
    floatx4 sacc[2][2] = {};
#pragma unroll
    for (int ks = 0; ks < 2; ++ks)
#pragma unroll
      for (int mi = 0; mi < 2; ++mi)
#pragma unroll
        for (int ni = 0; ni < 2; ++ni)
          sacc[mi][ni] = __builtin_amdgcn_mfma_f32_16x16x32_bf16(qf[mi][ks], kf[ni][ks], sacc[mi][ni], 0, 0, 0);

    // prefetch next-tile K (overwrite: old value dead after QK)
#pragma unroll
    for (int ni = 0; ni < 2; ++ni)
#pragma unroll
      for (int ks = 0; ks < 2; ++ks)
        kf[ni][ks] = *(const bf16x8*)&Kb[tn + (ks * 2 + ni) * 512];

    // p = exp2(s - EXP_BIAS), store to per-wave LDS (same-wave RAW only)
#pragma unroll
    for (int mi = 0; mi < 2; ++mi)
#pragma unroll
      for (int ni = 0; ni < 2; ++ni)
#pragma unroll
        for (int r = 0; r < 4; ++r) {
          float p = exp2f(sacc[mi][ni][r] - EXP_BIAS);
          Pw[(mi * 16 + quad * 4 + r) * 40 + ni * 16 + l15] = __float2bfloat16(p);
        }

    // read P back in A-layout
    bf16x8 pf[2];
#pragma unroll
    for (int mi = 0; mi < 2; ++mi)
      pf[mi] = *(const bf16x8*)&Pw[(mi * 16 + l15) * 40 + quad * 8];

    // row-sums via ones-MFMA
#pragma unroll
    for (int mi = 0; mi < 2; ++mi)
      lsum[mi] = __builtin_amdgcn_mfma_f32_16x16x32_bf16(pf[mi], ones_f, lsum[mi], 0, 0, 0);

    // O += P V on this tile's V frags
#pragma unroll
    for (int nd = 0; nd < 4; ++nd)
#pragma unroll
      for (int mi = 0; mi < 2; ++mi)
        o[mi][nd] = __builtin_amdgcn_mfma_f32_16x16x32_bf16(pf[mi], vf[nd], o[mi][nd], 0, 0, 0);

    // prefetch next-tile V (overwrite: old value dead after PV)
#pragma unroll
    for (int nd = 0; nd < 4; ++nd)
      vf[nd] = *(const bf16x8*)&Vb[tn + nd * 512];
  }

  // ---- split-K combine via LDS ----
  __syncthreads();  // all waves done with Pw before reuse as Obuf
  if (ksplit == 1) {
    float* Ob = (float*)smem + qw * (32 * 68);
#pragma unroll
    for (int mi = 0; mi < 2; ++mi)
#pragma unroll
      for (int nd = 0; nd < 4; ++nd)
#pragma unroll
        for (int r = 0; r < 4; ++r)
          Ob[(mi * 16 + quad * 4 + r) * 68 + nd * 16 + l15] = o[mi][nd][r];
    if (l15 == 0) {
#pragma unroll
      for (int mi = 0; mi < 2; ++mi)
#pragma unroll
        for (int r = 0; r < 4; ++r)
          Lbuf[qw][mi * 16 + quad * 4 + r] = lsum[mi][r];
    }
  }
  __syncthreads();
  if (ksplit == 0) {
    const float* Ob = (const float*)smem + qw * (32 * 68);
#pragma unroll
    for (int mi = 0; mi < 2; ++mi) {
      float linv[4];
#pragma unroll
      for (int r = 0; r < 4; ++r) {
        float lq = __shfl(lsum[mi][r], lane & 48, 64) + Lbuf[qw][mi * 16 + quad * 4 + r];
        linv[r] = 1.0f / lq;
      }
#pragma unroll
      for (int nd = 0; nd < 4; ++nd) {
#pragma unroll
        for (int r = 0; r < 4; ++r) {
          int rl = mi * 16 + quad * 4 + r;
          int qrow = q0 + qw * 32 + rl;
          int dd = nd * 16 + l15;
          float vv = (o[mi][nd][r] + Ob[rl * 68 + dd]) * linv[r];
          AO[(((size_t)b * S_LEN + qrow) << 10) + h * DH + dd] = __float2bfloat16(vv);
        }
      }
    }
  }
}

// ---------------- 4. output projection GEMM (128x64, BK=32) -> fp32 ----------------
__global__ __launch_bounds__(256) void gemm_out(
    const hbf* __restrict__ A, const hbf* __restrict__ Wt,
    const float* __restrict__ bias, float* __restrict__ Out) {
  __shared__ __align__(16) hbf As[128 * 32];
  __shared__ __align__(16) hbf Bs[64 * 32];

  const int tid = threadIdx.x;
  const int lane = tid & 63, wave = tid >> 6;
  const int l15 = lane & 15, quad = lane >> 4;
  const int wm = wave >> 1, wn = wave & 1;
  const int m0 = blockIdx.x * 128, n0 = blockIdx.y * 64;

  floatx4 acc[4][2] = {};

#pragma unroll 1
  for (int k0 = 0; k0 < DM; k0 += 32) {
#pragma unroll
    for (int it = 0; it < 2; ++it) {
      int c = tid + it * 256;
      int row = c >> 2, cc = (c & 3) << 3;
      gload_lds16(&A[(size_t)(m0 + row) * DM + k0 + cc], &As[row * 32 + cc]);
    }
    {
      int row = tid >> 2, cc = (tid & 3) << 3;
      gload_lds16(&Wt[(size_t)(n0 + row) * DM + k0 + cc], &Bs[row * 32 + cc]);
    }
    __syncthreads();
    bf16x8 af[4], bfr[2];
#pragma unroll
    for (int mi = 0; mi < 4; ++mi)
      af[mi] = *(const bf16x8*)&As[(wm * 64 + mi * 16 + l15) * 32 + quad * 8];
#pragma unroll
    for (int ni = 0; ni < 2; ++ni)
      bfr[ni] = *(const bf16x8*)&Bs[(wn * 32 + ni * 16 + l15) * 32 + quad * 8];
#pragma unroll
    for (int mi = 0; mi < 4; ++mi)
#pragma unroll
      for (int ni = 0; ni < 2; ++ni)
        acc[mi][ni] = __builtin_amdgcn_mfma_f32_16x16x32_bf16(af[mi], bfr[ni], acc[mi][ni], 0, 0, 0);
    __syncthreads();
  }

#pragma unroll
  for (int mi = 0; mi < 4; ++mi) {
#pragma unroll
    for (int ni = 0; ni < 2; ++ni) {
      int col = n0 + wn * 32 + ni * 16 + l15;
      float bb_ = bias[col];
#pragma unroll
      for (int r = 0; r < 4; ++r) {
        int row = m0 + wm * 64 + mi * 16 + quad * 4 + r;
        Out[(size_t)row * DM + col] = acc[mi][ni][r] + bb_;
      }
    }
  }
}

// ---------------- launch ----------------
extern "C" void kernel_launch(void* const* d_in, const int* in_sizes, int n_in,
                              void* d_out, int out_size, void* d_ws, size_t ws_size,
                              hipStream_t stream) {
  const float* v  = (const float*)d_in[0];
  const float* k  = (const float*)d_in[1];
  const float* q  = (const float*)d_in[2];
  const float* wq = (const float*)d_in[3];
  const float* bq = (const float*)d_in[4];
  const float* wk = (const float*)d_in[5];
  const float* bk = (const float*)d_in[6];
  const float* wv = (const float*)d_in[7];
  const float* bv = (const float*)d_in[8];
  const float* wo = (const float*)d_in[9];
  const float* bo = (const float*)d_in[10];

  const size_t NX = (size_t)MROWS * DM;  // 4M elems
  const size_t NW = (size_t)DM * DM;     // 1M elems
  hbf* base = (hbf*)d_ws;
  hbf* Xq  = base;
  hbf* Xk  = Xq + NX;
  hbf* Xv  = Xk + NX;
  hbf* Wqt = Xv + NX;
  hbf* Wkt = Wqt + NW;
  hbf* Wvt = Wkt + NW;
  hbf* Wot = Wvt + NW;
  hbf* Qh  = Wot + NW;
  hbf* Kf  = Qh + NX;
  hbf* Vf  = Kf + NX;
  hbf* AO  = Vf + NX;

  cvt3w<<<dim3(4096, 4), 256, 0, stream>>>(q, k, v, Xq, Xk, Xv,
                                           wq, wk, wv, wo, Wqt, Wkt, Wvt, Wot);
  gemm_qkv<<<dim3(32, 8, 3), 256, 0, stream>>>(Xq, Xk, Xv, Wqt, Wkt, Wvt, bq, bk, bv, Qh, Kf, Vf);
  flash_attn<<<1024, 256, 0, stream>>>(Qh, Kf, Vf, AO);
  gemm_out<<<dim3(32, 16), 256, 0, stream>>>(AO, Wot, bo, (float*)d_out);
}

// Round 7
// 242.242 us; speedup vs baseline: 1.2532x; 1.0504x over previous
//
#include <hip/hip_runtime.h>
#include <hip/hip_bf16.h>

#define S_LEN 2048
#define DM 1024
#define NH 16
#define DH 64
#define MROWS 4096  // B*S

typedef __hip_bfloat16 hbf;
typedef __attribute__((ext_vector_type(4))) float floatx4;
typedef __bf16 bf16x8 __attribute__((ext_vector_type(8)));

#define QSCALE 0.18033688f   // 0.125 * log2(e)  (score in log2 domain)
#define EXP_BIAS 5.77078016f // 4 * log2(e)

// A/B fragment-linear layout: value T[row16*16+l15][kb*32+quad*8+j] lives at
// frag (row16*(K/32) + kb)*512 + (quad*16+l15)*8 + j  -- every MFMA fragment
// is a contiguous 1KB run, loaded as base + lane*16B (fully coalesced).

// ---------------- 1. fused: X -> A-frag-linear bf16 + W -> B-frag-linear bf16 ----------------
__global__ __launch_bounds__(256) void cvt3w(
    const float* __restrict__ q, const float* __restrict__ k, const float* __restrict__ v,
    hbf* __restrict__ Xqh, hbf* __restrict__ Xkh, hbf* __restrict__ Xvh,
    const float* __restrict__ wq, const float* __restrict__ wk,
    const float* __restrict__ wv, const float* __restrict__ wo,
    hbf* __restrict__ Wqh, hbf* __restrict__ Wkh,
    hbf* __restrict__ Wvh, hbf* __restrict__ Woh) {
  __shared__ float tile[64][65];
  const int t = threadIdx.x;
  if (blockIdx.y < 3) {
    // X path: 64 rows x 64 k tile -> 8 fragments of 1KB
    const float* src; hbf* dst;
    switch (blockIdx.y) {
      case 0:  src = q; dst = Xqh; break;
      case 1:  src = k; dst = Xkh; break;
      default: src = v; dst = Xvh; break;
    }
    const int mt = blockIdx.x >> 4, kt = blockIdx.x & 15;
    const int s0 = mt * 64, k0 = kt * 64;
    const int col = t & 63, rb = t >> 6;
#pragma unroll
    for (int i = 0; i < 16; ++i) {
      int row = i * 4 + rb;
      tile[row][col] = src[(size_t)(s0 + row) * DM + k0 + col];
    }
    __syncthreads();
    const int lanep = t & 63, l15p = lanep & 15, quadp = lanep >> 4;
#pragma unroll
    for (int it = 0; it < 2; ++it) {
      int fl = (t >> 6) * 2 + it;     // 0..7
      int fm = fl >> 1, fk = fl & 1;
      union { hbf h[8]; uint4 u; } pk;
#pragma unroll
      for (int j = 0; j < 8; ++j)
        pk.h[j] = __float2bfloat16(tile[fm * 16 + l15p][fk * 32 + quadp * 8 + j]);
      size_t base = ((size_t)(mt * 4 + fm) * 32 + (kt * 2 + fk)) * 512 + lanep * 8;
      *(uint4*)&dst[base] = pk.u;
    }
    return;
  }
  // W path: transpose 64x64 tile, write B-frag-linear
  const float* W; hbf* Wh;
  switch (blockIdx.x >> 8) {
    case 0:  W = wq; Wh = Wqh; break;
    case 1:  W = wk; Wh = Wkh; break;
    case 2:  W = wv; Wh = Wvh; break;
    default: W = wo; Wh = Woh; break;
  }
  const int t8 = blockIdx.x & 255;
  const int n0 = (t8 & 15) * 64, k0 = (t8 >> 4) * 64;
  const int col = t & 63, rb = t >> 6;
#pragma unroll
  for (int i = 0; i < 16; ++i) {
    int row = i * 4 + rb;
    tile[row][col] = W[(size_t)(k0 + row) * DM + n0 + col];
  }
  __syncthreads();
#pragma unroll
  for (int i = 0; i < 16; ++i) {
    int rowi = i * 4 + rb;           // n-local
    int nn = n0 + rowi, kk = k0 + col;
    size_t idx = ((size_t)(nn >> 4) * 32 + (kk >> 5)) * 512 +
                 ((((kk >> 3) & 3) * 16 + (nn & 15)) * 8) + (kk & 7);
    Wh[idx] = __float2bfloat16(tile[col][rowi]);
  }
}

// ---------------- 2. QKV projection GEMM v2: no LDS, no barriers ----------------
// 4 waves x (64x64) tiles; A/B read as 1KB fragments, register double-buffered.
// Q: scaled by QSCALE, (B,H,S,64). K,V: fragment-linear for flash.
__global__ __launch_bounds__(256) void gemm_qkv(
    const hbf* __restrict__ Xqh, const hbf* __restrict__ Xkh, const hbf* __restrict__ Xvh,
    const hbf* __restrict__ Wqh, const hbf* __restrict__ Wkh, const hbf* __restrict__ Wvh,
    const float* __restrict__ bq, const float* __restrict__ bk, const float* __restrict__ bv,
    hbf* __restrict__ Qh, hbf* __restrict__ Kf, hbf* __restrict__ Vf) {
  const int id = blockIdx.x;             // 768
  const int x = id & 7, idx = id >> 3;   // XCD x gets m-slice [x*512, x*512+512)
  const int z = idx >> 5, rem = idx & 31;
  const int nblk = rem >> 1, mblk = rem & 1;

  const hbf* Ah; const hbf* Bh; const float* bias; hbf* Out; float oscale;
  if (z == 0)      { Ah = Xqh; Bh = Wqh; bias = bq; Out = Qh; oscale = QSCALE; }
  else if (z == 1) { Ah = Xkh; Bh = Wkh; bias = bk; Out = Kf; oscale = 1.0f; }
  else             { Ah = Xvh; Bh = Wvh; bias = bv; Out = Vf; oscale = 1.0f; }

  const int tid = threadIdx.x;
  const int lane = tid & 63, wave = tid >> 6;
  const int l15 = lane & 15, quad = lane >> 4;
  const int M0 = x * 512 + mblk * 256 + wave * 64;
  const int n0 = nblk * 64;

  const hbf* ap = Ah + (size_t)(M0 >> 4) * 32 * 512 + lane * 8;  // + (mi*32 + kb)*512
  const hbf* bp = Bh + (size_t)(n0 >> 4) * 32 * 512 + lane * 8;

  floatx4 acc[4][4] = {};
  bf16x8 a0[4], b0[4], a1[4], b1[4];
#pragma unroll
  for (int i = 0; i < 4; ++i) {
    a0[i] = *(const bf16x8*)&ap[(size_t)i * 16384];
    b0[i] = *(const bf16x8*)&bp[(size_t)i * 16384];
  }

#pragma unroll 1
  for (int kb = 0; kb < 32; kb += 2) {
#pragma unroll
    for (int i = 0; i < 4; ++i) {
      a1[i] = *(const bf16x8*)&ap[(size_t)i * 16384 + (kb + 1) * 512];
      b1[i] = *(const bf16x8*)&bp[(size_t)i * 16384 + (kb + 1) * 512];
    }
#pragma unroll
    for (int mi = 0; mi < 4; ++mi)
#pragma unroll
      for (int ni = 0; ni < 4; ++ni)
        acc[mi][ni] = __builtin_amdgcn_mfma_f32_16x16x32_bf16(a0[mi], b0[ni], acc[mi][ni], 0, 0, 0);
    const int k2 = (kb + 2) & 31;  // wrap-safe dummy on last iter
#pragma unroll
    for (int i = 0; i < 4; ++i) {
      a0[i] = *(const bf16x8*)&ap[(size_t)i * 16384 + k2 * 512];
      b0[i] = *(const bf16x8*)&bp[(size_t)i * 16384 + k2 * 512];
    }
#pragma unroll
    for (int mi = 0; mi < 4; ++mi)
#pragma unroll
      for (int ni = 0; ni < 4; ++ni)
        acc[mi][ni] = __builtin_amdgcn_mfma_f32_16x16x32_bf16(a1[mi], b1[ni], acc[mi][ni], 0, 0, 0);
  }

#pragma unroll
  for (int mi = 0; mi < 4; ++mi) {
#pragma unroll
    for (int ni = 0; ni < 4; ++ni) {
      int col = n0 + ni * 16 + l15;
      float bb_ = bias[col];
#pragma unroll
      for (int r = 0; r < 4; ++r) {
        int row = M0 + mi * 16 + quad * 4 + r;
        float vv = (acc[mi][ni][r] + bb_) * oscale;
        int b = row >> 11, s = row & 2047, h = col >> 6, dd = col & 63;
        int bh = b * NH + h;
        size_t idxo;
        if (z == 1) {
          int kt = s >> 5, nif = (s >> 4) & 1, fl15 = s & 15;
          int ksf = dd >> 5, fquad = (dd >> 3) & 3, e = dd & 7;
          idxo = (((size_t)bh * 64 + kt) * 4 + ksf * 2 + nif) * 512 + (fquad * 16 + fl15) * 8 + e;
        } else if (z == 2) {
          int kt = s >> 5, fquad = (s >> 3) & 3, e = s & 7;
          int nd = dd >> 4, fl15 = dd & 15;
          idxo = (((size_t)bh * 64 + kt) * 4 + nd) * 512 + (fquad * 16 + fl15) * 8 + e;
        } else {
          idxo = (((size_t)bh * S_LEN + s) << 6) + dd;
        }
        Out[idxo] = __float2bfloat16(vv);
      }
    }
  }
}

// ---------------- 3. flash attention v7: fragment-linear K/V, AO -> A-frag-linear ----------------
__global__ __launch_bounds__(256, 4) void flash_attn(
    const hbf* __restrict__ Qh, const hbf* __restrict__ Kf,
    const hbf* __restrict__ Vf, hbf* __restrict__ AO) {
  const int id = blockIdx.x;
  const int bh = (id & 7) * 4 + (id >> 8);     // XCD-local bh group
  const int q0 = ((id >> 3) & 31) * 64;
  const int b = bh >> 4, h = bh & 15;
  const int tid = threadIdx.x;
  const int lane = tid & 63, wave = tid >> 6;
  const int qw = wave & 1;       // q-half within block
  const int ksplit = wave >> 1;  // key half
  const int l15 = lane & 15, quad = lane >> 4;

  __shared__ __align__(16) unsigned char smem[17408];
  __shared__ float Lbuf[2][32];
  hbf* Pw = (hbf*)(smem + wave * 2560);

  const size_t qbase = (((size_t)bh) * S_LEN + q0 + qw * 32) * DH;
  bf16x8 qf[2][2];
#pragma unroll
  for (int mi = 0; mi < 2; ++mi)
#pragma unroll
    for (int ks = 0; ks < 2; ++ks)
      qf[mi][ks] = *(const bf16x8*)&Qh[qbase + (size_t)(mi * 16 + l15) * DH + ks * 32 + quad * 8];

  bf16x8 ones_f;
  {
    const __bf16 ov = (l15 == 0) ? (__bf16)1.0f : (__bf16)0.0f;
#pragma unroll
    for (int j = 0; j < 8; ++j) ones_f[j] = ov;
  }

  floatx4 o[2][4] = {};
  floatx4 lsum[2] = {};

  const hbf* Kb = Kf + ((size_t)bh * 64 + ksplit * 32) * 2048 + lane * 8;
  const hbf* Vb = Vf + ((size_t)bh * 64 + ksplit * 32) * 2048 + lane * 8;

  bf16x8 kf[2][2], vf[4];
#pragma unroll
  for (int ni = 0; ni < 2; ++ni)
#pragma unroll
    for (int ks = 0; ks < 2; ++ks)
      kf[ni][ks] = *(const bf16x8*)&Kb[(ks * 2 + ni) * 512];
#pragma unroll
  for (int nd = 0; nd < 4; ++nd)
    vf[nd] = *(const bf16x8*)&Vb[nd * 512];

#pragma unroll 1
  for (int it = 0; it < 32; ++it) {
    const int tn = (it == 31) ? 0 : (it + 1) * 2048;

    floatx4 sacc[2][2] = {};
#pragma unroll
    for (int ks = 0; ks < 2; ++ks)
#pragma unroll
      for (int mi = 0; mi < 2; ++mi)
#pragma unroll
        for (int ni = 0; ni < 2; ++ni)
          sacc[mi][ni] = __builtin_amdgcn_mfma_f32_16x16x32_bf16(qf[mi][ks], kf[ni][ks], sacc[mi][ni], 0, 0, 0);

#pragma unroll
    for (int ni = 0; ni < 2; ++ni)
#pragma unroll
      for (int ks = 0; ks < 2; ++ks)
        kf[ni][ks] = *(const bf16x8*)&Kb[tn + (ks * 2 + ni) * 512];

#pragma unroll
    for (int mi = 0; mi < 2; ++mi)
#pragma unroll
      for (int ni = 0; ni < 2; ++ni)
#pragma unroll
        for (int r = 0; r < 4; ++r) {
          float p = exp2f(sacc[mi][ni][r] - EXP_BIAS);
          Pw[(mi * 16 + quad * 4 + r) * 40 + ni * 16 + l15] = __float2bfloat16(p);
        }

    bf16x8 pf[2];
#pragma unroll
    for (int mi = 0; mi < 2; ++mi)
      pf[mi] = *(const bf16x8*)&Pw[(mi * 16 + l15) * 40 + quad * 8];

#pragma unroll
    for (int mi = 0; mi < 2; ++mi)
      lsum[mi] = __builtin_amdgcn_mfma_f32_16x16x32_bf16(pf[mi], ones_f, lsum[mi], 0, 0, 0);

#pragma unroll
    for (int nd = 0; nd < 4; ++nd)
#pragma unroll
      for (int mi = 0; mi < 2; ++mi)
        o[mi][nd] = __builtin_amdgcn_mfma_f32_16x16x32_bf16(pf[mi], vf[nd], o[mi][nd], 0, 0, 0);

#pragma unroll
    for (int nd = 0; nd < 4; ++nd)
      vf[nd] = *(const bf16x8*)&Vb[tn + nd * 512];
  }

  // ---- split-K combine via LDS ----
  __syncthreads();
  if (ksplit == 1) {
    float* Ob = (float*)smem + qw * (32 * 68);
#pragma unroll
    for (int mi = 0; mi < 2; ++mi)
#pragma unroll
      for (int nd = 0; nd < 4; ++nd)
#pragma unroll
        for (int r = 0; r < 4; ++r)
          Ob[(mi * 16 + quad * 4 + r) * 68 + nd * 16 + l15] = o[mi][nd][r];
    if (l15 == 0) {
#pragma unroll
      for (int mi = 0; mi < 2; ++mi)
#pragma unroll
        for (int r = 0; r < 4; ++r)
          Lbuf[qw][mi * 16 + quad * 4 + r] = lsum[mi][r];
    }
  }
  __syncthreads();
  if (ksplit == 0) {
    const float* Ob = (const float*)smem + qw * (32 * 68);
#pragma unroll
    for (int mi = 0; mi < 2; ++mi) {
      float linv[4];
#pragma unroll
      for (int r = 0; r < 4; ++r) {
        float lq = __shfl(lsum[mi][r], lane & 48, 64) + Lbuf[qw][mi * 16 + quad * 4 + r];
        linv[r] = 1.0f / lq;
      }
      const int m16 = (b * S_LEN + q0 + qw * 32 + mi * 16) >> 4;
#pragma unroll
      for (int nd = 0; nd < 4; ++nd) {
        const int kb = h * 2 + (nd >> 1);
        const int qa = ((nd & 1) << 1) + (l15 >> 3);
        const int dd = nd * 16 + l15;
#pragma unroll
        for (int r = 0; r < 4; ++r) {
          int rl = mi * 16 + quad * 4 + r;
          float vv = (o[mi][nd][r] + Ob[rl * 68 + dd]) * linv[r];
          // AO in A-frag-linear layout for gemm_out
          size_t idxo = ((size_t)m16 * 32 + kb) * 512 + (qa * 16 + quad * 4 + r) * 8 + (l15 & 7);
          AO[idxo] = __float2bfloat16(vv);
        }
      }
    }
  }
}

// ---------------- 4. output projection GEMM v2: no LDS, no barriers -> fp32 ----------------
// 32x64 wave-tiles (2048 waves = 8/CU). A = AO-hat (frag-linear), B = Wo-hat.
__global__ __launch_bounds__(256) void gemm_out(
    const hbf* __restrict__ Ah, const hbf* __restrict__ Bh,
    const float* __restrict__ bias, float* __restrict__ Out) {
  const int id = blockIdx.x;             // 512
  const int x = id & 7, idx = id >> 3;   // XCD m-slice
  const int nblk = idx >> 3, mblk = idx & 7;
  const int tid = threadIdx.x;
  const int lane = tid & 63, wave = tid >> 6;
  const int l15 = lane & 15, quad = lane >> 4;
  const int wm = wave >> 1, wn = wave & 1;
  const int M0 = x * 512 + mblk * 64 + wm * 32;
  const int n0 = nblk * 128 + wn * 64;

  const hbf* ap = Ah + (size_t)(M0 >> 4) * 32 * 512 + lane * 8;
  const hbf* bp = Bh + (size_t)(n0 >> 4) * 32 * 512 + lane * 8;

  floatx4 acc[2][4] = {};
  bf16x8 a0[2], b0[4], a1[2], b1[4];
#pragma unroll
  for (int i = 0; i < 2; ++i) a0[i] = *(const bf16x8*)&ap[(size_t)i * 16384];
#pragma unroll
  for (int i = 0; i < 4; ++i) b0[i] = *(const bf16x8*)&bp[(size_t)i * 16384];

#pragma unroll 1
  for (int kb = 0; kb < 32; kb += 2) {
#pragma unroll
    for (int i = 0; i < 2; ++i) a1[i] = *(const bf16x8*)&ap[(size_t)i * 16384 + (kb + 1) * 512];
#pragma unroll
    for (int i = 0; i < 4; ++i) b1[i] = *(const bf16x8*)&bp[(size_t)i * 16384 + (kb + 1) * 512];
#pragma unroll
    for (int mi = 0; mi < 2; ++mi)
#pragma unroll
      for (int ni = 0; ni < 4; ++ni)
        acc[mi][ni] = __builtin_amdgcn_mfma_f32_16x16x32_bf16(a0[mi], b0[ni], acc[mi][ni], 0, 0, 0);
    const int k2 = (kb + 2) & 31;
#pragma unroll
    for (int i = 0; i < 2; ++i) a0[i] = *(const bf16x8*)&ap[(size_t)i * 16384 + k2 * 512];
#pragma unroll
    for (int i = 0; i < 4; ++i) b0[i] = *(const bf16x8*)&bp[(size_t)i * 16384 + k2 * 512];
#pragma unroll
    for (int mi = 0; mi < 2; ++mi)
#pragma unroll
      for (int ni = 0; ni < 4; ++ni)
        acc[mi][ni] = __builtin_amdgcn_mfma_f32_16x16x32_bf16(a1[mi], b1[ni], acc[mi][ni], 0, 0, 0);
  }

#pragma unroll
  for (int mi = 0; mi < 2; ++mi) {
#pragma unroll
    for (int ni = 0; ni < 4; ++ni) {
      int col = n0 + ni * 16 + l15;
      float bb_ = bias[col];
#pragma unroll
      for (int r = 0; r < 4; ++r) {
        int row = M0 + mi * 16 + quad * 4 + r;
        Out[(size_t)row * DM + col] = acc[mi][ni][r] + bb_;
      }
    }
  }
}

// ---------------- launch ----------------
extern "C" void kernel_launch(void* const* d_in, const int* in_sizes, int n_in,
                              void* d_out, int out_size, void* d_ws, size_t ws_size,
                              hipStream_t stream) {
  const float* v  = (const float*)d_in[0];
  const float* k  = (const float*)d_in[1];
  const float* q  = (const float*)d_in[2];
  const float* wq = (const float*)d_in[3];
  const float* bq = (const float*)d_in[4];
  const float* wk = (const float*)d_in[5];
  const float* bk = (const float*)d_in[6];
  const float* wv = (const float*)d_in[7];
  const float* bv = (const float*)d_in[8];
  const float* wo = (const float*)d_in[9];
  const float* bo = (const float*)d_in[10];

  const size_t NX = (size_t)MROWS * DM;  // 4M elems
  const size_t NW = (size_t)DM * DM;     // 1M elems
  hbf* base = (hbf*)d_ws;
  hbf* Xqh = base;
  hbf* Xkh = Xqh + NX;
  hbf* Xvh = Xkh + NX;
  hbf* Wqh = Xvh + NX;
  hbf* Wkh = Wqh + NW;
  hbf* Wvh = Wkh + NW;
  hbf* Woh = Wvh + NW;
  hbf* Qh  = Woh + NW;
  hbf* Kf  = Qh + NX;
  hbf* Vf  = Kf + NX;
  hbf* AOh = Vf + NX;

  cvt3w<<<dim3(1024, 4), 256, 0, stream>>>(q, k, v, Xqh, Xkh, Xvh,
                                           wq, wk, wv, wo, Wqh, Wkh, Wvh, Woh);
  gemm_qkv<<<768, 256, 0, stream>>>(Xqh, Xkh, Xvh, Wqh, Wkh, Wvh, bq, bk, bv, Qh, Kf, Vf);
  flash_attn<<<1024, 256, 0, stream>>>(Qh, Kf, Vf, AOh);
  gemm_out<<<512, 256, 0, stream>>>(AOh, Woh, bo, (float*)d_out);
}

// Round 8
// 226.870 us; speedup vs baseline: 1.3381x; 1.0678x over previous
//
#include <hip/hip_runtime.h>
#include <hip/hip_bf16.h>

#define S_LEN 2048
#define DM 1024
#define NH 16
#define DH 64
#define MROWS 4096  // B*S

typedef __hip_bfloat16 hbf;
typedef __attribute__((ext_vector_type(4))) float floatx4;
typedef __bf16 bf16x8 __attribute__((ext_vector_type(8)));

#define QSCALE 0.18033688f   // 0.125 * log2(e)  (score in log2 domain; exp2 is raw, softmax shift-invariant)

// A/B fragment-linear layout: value T[row16*16+l15][kb*32+quad*8+j] lives at
// frag (row16*(K/32) + kb)*512 + (quad*16+l15)*8 + j  -- every MFMA fragment
// is a contiguous 1KB run, loaded as base + lane*16B (fully coalesced).

// ---------------- 1. fused: X -> A-frag-linear bf16 + W -> B-frag-linear bf16 ----------------
__global__ __launch_bounds__(256) void cvt3w(
    const float* __restrict__ q, const float* __restrict__ k, const float* __restrict__ v,
    hbf* __restrict__ Xqh, hbf* __restrict__ Xkh, hbf* __restrict__ Xvh,
    const float* __restrict__ wq, const float* __restrict__ wk,
    const float* __restrict__ wv, const float* __restrict__ wo,
    hbf* __restrict__ Wqh, hbf* __restrict__ Wkh,
    hbf* __restrict__ Wvh, hbf* __restrict__ Woh) {
  __shared__ float tile[64][65];
  const int t = threadIdx.x;
  if (blockIdx.y < 3) {
    // X path: 64 rows x 64 k tile -> 8 fragments of 1KB
    const float* src; hbf* dst;
    switch (blockIdx.y) {
      case 0:  src = q; dst = Xqh; break;
      case 1:  src = k; dst = Xkh; break;
      default: src = v; dst = Xvh; break;
    }
    const int mt = blockIdx.x >> 4, kt = blockIdx.x & 15;
    const int s0 = mt * 64, k0 = kt * 64;
    const int col = t & 63, rb = t >> 6;
#pragma unroll
    for (int i = 0; i < 16; ++i) {
      int row = i * 4 + rb;
      tile[row][col] = src[(size_t)(s0 + row) * DM + k0 + col];
    }
    __syncthreads();
    const int lanep = t & 63, l15p = lanep & 15, quadp = lanep >> 4;
#pragma unroll
    for (int it = 0; it < 2; ++it) {
      int fl = (t >> 6) * 2 + it;     // 0..7
      int fm = fl >> 1, fk = fl & 1;
      union { hbf h[8]; uint4 u; } pk;
#pragma unroll
      for (int j = 0; j < 8; ++j)
        pk.h[j] = __float2bfloat16(tile[fm * 16 + l15p][fk * 32 + quadp * 8 + j]);
      size_t base = ((size_t)(mt * 4 + fm) * 32 + (kt * 2 + fk)) * 512 + lanep * 8;
      *(uint4*)&dst[base] = pk.u;
    }
    return;
  }
  // W path: transpose 64x64 tile, write B-frag-linear
  const float* W; hbf* Wh;
  switch (blockIdx.x >> 8) {
    case 0:  W = wq; Wh = Wqh; break;
    case 1:  W = wk; Wh = Wkh; break;
    case 2:  W = wv; Wh = Wvh; break;
    default: W = wo; Wh = Woh; break;
  }
  const int t8 = blockIdx.x & 255;
  const int n0 = (t8 & 15) * 64, k0 = (t8 >> 4) * 64;
  const int col = t & 63, rb = t >> 6;
#pragma unroll
  for (int i = 0; i < 16; ++i) {
    int row = i * 4 + rb;
    tile[row][col] = W[(size_t)(k0 + row) * DM + n0 + col];
  }
  __syncthreads();
#pragma unroll
  for (int i = 0; i < 16; ++i) {
    int rowi = i * 4 + rb;           // n-local
    int nn = n0 + rowi, kk = k0 + col;
    size_t idx = ((size_t)(nn >> 4) * 32 + (kk >> 5)) * 512 +
                 ((((kk >> 3) & 3) * 16 + (nn & 15)) * 8) + (kk & 7);
    Wh[idx] = __float2bfloat16(tile[col][rowi]);
  }
}

// ---------------- 2. QKV projection GEMM v2: no LDS, no barriers ----------------
// 4 waves x (64x64) tiles; A/B read as 1KB fragments, register double-buffered.
// Q: scaled by QSCALE, (B,H,S,64). K,V: fragment-linear for flash.
// V-hat keys stored PERMUTED within each 32-key tile: p = 2*(u&15) + (u>>4),
// matching flash's packed-P column order (softmax sum is key-order invariant).
__global__ __launch_bounds__(256) void gemm_qkv(
    const hbf* __restrict__ Xqh, const hbf* __restrict__ Xkh, const hbf* __restrict__ Xvh,
    const hbf* __restrict__ Wqh, const hbf* __restrict__ Wkh, const hbf* __restrict__ Wvh,
    const float* __restrict__ bq, const float* __restrict__ bk, const float* __restrict__ bv,
    hbf* __restrict__ Qh, hbf* __restrict__ Kf, hbf* __restrict__ Vf) {
  const int id = blockIdx.x;             // 768
  const int x = id & 7, idx = id >> 3;   // XCD x gets m-slice [x*512, x*512+512)
  const int z = idx >> 5, rem = idx & 31;
  const int nblk = rem >> 1, mblk = rem & 1;

  const hbf* Ah; const hbf* Bh; const float* bias; hbf* Out; float oscale;
  if (z == 0)      { Ah = Xqh; Bh = Wqh; bias = bq; Out = Qh; oscale = QSCALE; }
  else if (z == 1) { Ah = Xkh; Bh = Wkh; bias = bk; Out = Kf; oscale = 1.0f; }
  else             { Ah = Xvh; Bh = Wvh; bias = bv; Out = Vf; oscale = 1.0f; }

  const int tid = threadIdx.x;
  const int lane = tid & 63, wave = tid >> 6;
  const int l15 = lane & 15, quad = lane >> 4;
  const int M0 = x * 512 + mblk * 256 + wave * 64;
  const int n0 = nblk * 64;

  const hbf* ap = Ah + (size_t)(M0 >> 4) * 32 * 512 + lane * 8;  // + (mi*32 + kb)*512
  const hbf* bp = Bh + (size_t)(n0 >> 4) * 32 * 512 + lane * 8;

  floatx4 acc[4][4] = {};
  bf16x8 a0[4], b0[4], a1[4], b1[4];
#pragma unroll
  for (int i = 0; i < 4; ++i) {
    a0[i] = *(const bf16x8*)&ap[(size_t)i * 16384];
    b0[i] = *(const bf16x8*)&bp[(size_t)i * 16384];
  }

#pragma unroll 1
  for (int kb = 0; kb < 32; kb += 2) {
#pragma unroll
    for (int i = 0; i < 4; ++i) {
      a1[i] = *(const bf16x8*)&ap[(size_t)i * 16384 + (kb + 1) * 512];
      b1[i] = *(const bf16x8*)&bp[(size_t)i * 16384 + (kb + 1) * 512];
    }
#pragma unroll
    for (int mi = 0; mi < 4; ++mi)
#pragma unroll
      for (int ni = 0; ni < 4; ++ni)
        acc[mi][ni] = __builtin_amdgcn_mfma_f32_16x16x32_bf16(a0[mi], b0[ni], acc[mi][ni], 0, 0, 0);
    const int k2 = (kb + 2) & 31;  // wrap-safe dummy on last iter
#pragma unroll
    for (int i = 0; i < 4; ++i) {
      a0[i] = *(const bf16x8*)&ap[(size_t)i * 16384 + k2 * 512];
      b0[i] = *(const bf16x8*)&bp[(size_t)i * 16384 + k2 * 512];
    }
#pragma unroll
    for (int mi = 0; mi < 4; ++mi)
#pragma unroll
      for (int ni = 0; ni < 4; ++ni)
        acc[mi][ni] = __builtin_amdgcn_mfma_f32_16x16x32_bf16(a1[mi], b1[ni], acc[mi][ni], 0, 0, 0);
  }

#pragma unroll
  for (int mi = 0; mi < 4; ++mi) {
#pragma unroll
    for (int ni = 0; ni < 4; ++ni) {
      int col = n0 + ni * 16 + l15;
      float bb_ = bias[col];
#pragma unroll
      for (int r = 0; r < 4; ++r) {
        int row = M0 + mi * 16 + quad * 4 + r;
        float vv = (acc[mi][ni][r] + bb_) * oscale;
        int b = row >> 11, s = row & 2047, h = col >> 6, dd = col & 63;
        int bh = b * NH + h;
        size_t idxo;
        if (z == 1) {
          int kt = s >> 5, nif = (s >> 4) & 1, fl15 = s & 15;
          int ksf = dd >> 5, fquad = (dd >> 3) & 3, e = dd & 7;
          idxo = (((size_t)bh * 64 + kt) * 4 + ksf * 2 + nif) * 512 + (fquad * 16 + fl15) * 8 + e;
        } else if (z == 2) {
          int kt = s >> 5, u = s & 31;
          int p = 2 * (u & 15) + (u >> 4);   // permuted key slot (matches packed P)
          int fquad = p >> 3, e = p & 7;
          int nd = dd >> 4, fl15 = dd & 15;
          idxo = (((size_t)bh * 64 + kt) * 4 + nd) * 512 + (fquad * 16 + fl15) * 8 + e;
        } else {
          idxo = (((size_t)bh * S_LEN + s) << 6) + dd;
        }
        Out[idxo] = __float2bfloat16(vv);
      }
    }
  }
}

// ---------------- 3. flash attention v8: bare v_exp, packed P stores ----------------
__global__ __launch_bounds__(256, 4) void flash_attn(
    const hbf* __restrict__ Qh, const hbf* __restrict__ Kf,
    const hbf* __restrict__ Vf, hbf* __restrict__ AO) {
  const int id = blockIdx.x;
  const int bh = (id & 7) * 4 + (id >> 8);     // XCD-local bh group
  const int q0 = ((id >> 3) & 31) * 64;
  const int b = bh >> 4, h = bh & 15;
  const int tid = threadIdx.x;
  const int lane = tid & 63, wave = tid >> 6;
  const int qw = wave & 1;       // q-half within block
  const int ksplit = wave >> 1;  // key half
  const int l15 = lane & 15, quad = lane >> 4;

  __shared__ __align__(16) unsigned char smem[17408];
  __shared__ float Lbuf[2][32];
  hbf* Pw = (hbf*)(smem + wave * 2560);

  const size_t qbase = (((size_t)bh) * S_LEN + q0 + qw * 32) * DH;
  bf16x8 qf[2][2];
#pragma unroll
  for (int mi = 0; mi < 2; ++mi)
#pragma unroll
    for (int ks = 0; ks < 2; ++ks)
      qf[mi][ks] = *(const bf16x8*)&Qh[qbase + (size_t)(mi * 16 + l15) * DH + ks * 32 + quad * 8];

  bf16x8 ones_f;
  {
    const __bf16 ov = (l15 == 0) ? (__bf16)1.0f : (__bf16)0.0f;
#pragma unroll
    for (int j = 0; j < 8; ++j) ones_f[j] = ov;
  }

  floatx4 o[2][4] = {};
  floatx4 lsum[2] = {};

  const hbf* Kb = Kf + ((size_t)bh * 64 + ksplit * 32) * 2048 + lane * 8;
  const hbf* Vb = Vf + ((size_t)bh * 64 + ksplit * 32) * 2048 + lane * 8;

  bf16x8 kf[2][2], vf[4];
#pragma unroll
  for (int ni = 0; ni < 2; ++ni)
#pragma unroll
    for (int ks = 0; ks < 2; ++ks)
      kf[ni][ks] = *(const bf16x8*)&Kb[(ks * 2 + ni) * 512];
#pragma unroll
  for (int nd = 0; nd < 4; ++nd)
    vf[nd] = *(const bf16x8*)&Vb[nd * 512];

#pragma unroll 1
  for (int it = 0; it < 32; ++it) {
    const int tn = (it == 31) ? 0 : (it + 1) * 2048;

    floatx4 sacc[2][2] = {};
#pragma unroll
    for (int ks = 0; ks < 2; ++ks)
#pragma unroll
      for (int mi = 0; mi < 2; ++mi)
#pragma unroll
        for (int ni = 0; ni < 2; ++ni)
          sacc[mi][ni] = __builtin_amdgcn_mfma_f32_16x16x32_bf16(qf[mi][ks], kf[ni][ks], sacc[mi][ni], 0, 0, 0);

#pragma unroll
    for (int ni = 0; ni < 2; ++ni)
#pragma unroll
      for (int ks = 0; ks < 2; ++ks)
        kf[ni][ks] = *(const bf16x8*)&Kb[tn + (ks * 2 + ni) * 512];

    // p = exp2(s) (raw v_exp; softmax shift-invariance makes the bias unnecessary)
    // packed pair (ni=0,1) -> one b32 store at permuted col 2*l15+ni
#pragma unroll
    for (int mi = 0; mi < 2; ++mi)
#pragma unroll
      for (int r = 0; r < 4; ++r) {
        union { hbf h2[2]; unsigned int u; } pk2;
        pk2.h2[0] = __float2bfloat16(__builtin_amdgcn_exp2f(sacc[mi][0][r]));
        pk2.h2[1] = __float2bfloat16(__builtin_amdgcn_exp2f(sacc[mi][1][r]));
        *(unsigned int*)&Pw[(mi * 16 + quad * 4 + r) * 40 + 2 * l15] = pk2.u;
      }

    bf16x8 pf[2];
#pragma unroll
    for (int mi = 0; mi < 2; ++mi)
      pf[mi] = *(const bf16x8*)&Pw[(mi * 16 + l15) * 40 + quad * 8];

#pragma unroll
    for (int mi = 0; mi < 2; ++mi)
      lsum[mi] = __builtin_amdgcn_mfma_f32_16x16x32_bf16(pf[mi], ones_f, lsum[mi], 0, 0, 0);

#pragma unroll
    for (int nd = 0; nd < 4; ++nd)
#pragma unroll
      for (int mi = 0; mi < 2; ++mi)
        o[mi][nd] = __builtin_amdgcn_mfma_f32_16x16x32_bf16(pf[mi], vf[nd], o[mi][nd], 0, 0, 0);

#pragma unroll
    for (int nd = 0; nd < 4; ++nd)
      vf[nd] = *(const bf16x8*)&Vb[tn + nd * 512];
  }

  // ---- split-K combine via LDS ----
  __syncthreads();
  if (ksplit == 1) {
    float* Ob = (float*)smem + qw * (32 * 68);
#pragma unroll
    for (int mi = 0; mi < 2; ++mi)
#pragma unroll
      for (int nd = 0; nd < 4; ++nd)
#pragma unroll
        for (int r = 0; r < 4; ++r)
          Ob[(mi * 16 + quad * 4 + r) * 68 + nd * 16 + l15] = o[mi][nd][r];
    if (l15 == 0) {
#pragma unroll
      for (int mi = 0; mi < 2; ++mi)
#pragma unroll
        for (int r = 0; r < 4; ++r)
          Lbuf[qw][mi * 16 + quad * 4 + r] = lsum[mi][r];
    }
  }
  __syncthreads();
  if (ksplit == 0) {
    const float* Ob = (const float*)smem + qw * (32 * 68);
#pragma unroll
    for (int mi = 0; mi < 2; ++mi) {
      float linv[4];
#pragma unroll
      for (int r = 0; r < 4; ++r) {
        float lq = __shfl(lsum[mi][r], lane & 48, 64) + Lbuf[qw][mi * 16 + quad * 4 + r];
        linv[r] = 1.0f / lq;
      }
      const int m16 = (b * S_LEN + q0 + qw * 32 + mi * 16) >> 4;
#pragma unroll
      for (int nd = 0; nd < 4; ++nd) {
        const int kb = h * 2 + (nd >> 1);
        const int qa = ((nd & 1) << 1) + (l15 >> 3);
        const int dd = nd * 16 + l15;
#pragma unroll
        for (int r = 0; r < 4; ++r) {
          int rl = mi * 16 + quad * 4 + r;
          float vv = (o[mi][nd][r] + Ob[rl * 68 + dd]) * linv[r];
          // AO in A-frag-linear layout for gemm_out
          size_t idxo = ((size_t)m16 * 32 + kb) * 512 + (qa * 16 + quad * 4 + r) * 8 + (l15 & 7);
          AO[idxo] = __float2bfloat16(vv);
        }
      }
    }
  }
}

// ---------------- 4. output projection GEMM v2: no LDS, no barriers -> fp32 ----------------
// 32x64 wave-tiles (2048 waves = 8/CU). A = AO-hat (frag-linear), B = Wo-hat.
__global__ __launch_bounds__(256) void gemm_out(
    const hbf* __restrict__ Ah, const hbf* __restrict__ Bh,
    const float* __restrict__ bias, float* __restrict__ Out) {
  const int id = blockIdx.x;             // 512
  const int x = id & 7, idx = id >> 3;   // XCD m-slice
  const int nblk = idx >> 3, mblk = idx & 7;
  const int tid = threadIdx.x;
  const int lane = tid & 63, wave = tid >> 6;
  const int l15 = lane & 15, quad = lane >> 4;
  const int wm = wave >> 1, wn = wave & 1;
  const int M0 = x * 512 + mblk * 64 + wm * 32;
  const int n0 = nblk * 128 + wn * 64;

  const hbf* ap = Ah + (size_t)(M0 >> 4) * 32 * 512 + lane * 8;
  const hbf* bp = Bh + (size_t)(n0 >> 4) * 32 * 512 + lane * 8;

  floatx4 acc[2][4] = {};
  bf16x8 a0[2], b0[4], a1[2], b1[4];
#pragma unroll
  for (int i = 0; i < 2; ++i) a0[i] = *(const bf16x8*)&ap[(size_t)i * 16384];
#pragma unroll
  for (int i = 0; i < 4; ++i) b0[i] = *(const bf16x8*)&bp[(size_t)i * 16384];

#pragma unroll 1
  for (int kb = 0; kb < 32; kb += 2) {
#pragma unroll
    for (int i = 0; i < 2; ++i) a1[i] = *(const bf16x8*)&ap[(size_t)i * 16384 + (kb + 1) * 512];
#pragma unroll
    for (int i = 0; i < 4; ++i) b1[i] = *(const bf16x8*)&bp[(size_t)i * 16384 + (kb + 1) * 512];
#pragma unroll
    for (int mi = 0; mi < 2; ++mi)
#pragma unroll
      for (int ni = 0; ni < 4; ++ni)
        acc[mi][ni] = __builtin_amdgcn_mfma_f32_16x16x32_bf16(a0[mi], b0[ni], acc[mi][ni], 0, 0, 0);
    const int k2 = (kb + 2) & 31;
#pragma unroll
    for (int i = 0; i < 2; ++i) a0[i] = *(const bf16x8*)&ap[(size_t)i * 16384 + k2 * 512];
#pragma unroll
    for (int i = 0; i < 4; ++i) b0[i] = *(const bf16x8*)&bp[(size_t)i * 16384 + k2 * 512];
#pragma unroll
    for (int mi = 0; mi < 2; ++mi)
#pragma unroll
      for (int ni = 0; ni < 4; ++ni)
        acc[mi][ni] = __builtin_amdgcn_mfma_f32_16x16x32_bf16(a1[mi], b1[ni], acc[mi][ni], 0, 0, 0);
  }

#pragma unroll
  for (int mi = 0; mi < 2; ++mi) {
#pragma unroll
    for (int ni = 0; ni < 4; ++ni) {
      int col = n0 + ni * 16 + l15;
      float bb_ = bias[col];
#pragma unroll
      for (int r = 0; r < 4; ++r) {
        int row = M0 + mi * 16 + quad * 4 + r;
        Out[(size_t)row * DM + col] = acc[mi][ni][r] + bb_;
      }
    }
  }
}

// ---------------- launch ----------------
extern "C" void kernel_launch(void* const* d_in, const int* in_sizes, int n_in,
                              void* d_out, int out_size, void* d_ws, size_t ws_size,
                              hipStream_t stream) {
  const float* v  = (const float*)d_in[0];
  const float* k  = (const float*)d_in[1];
  const float* q  = (const float*)d_in[2];
  const float* wq = (const float*)d_in[3];
  const float* bq = (const float*)d_in[4];
  const float* wk = (const float*)d_in[5];
  const float* bk = (const float*)d_in[6];
  const float* wv = (const float*)d_in[7];
  const float* bv = (const float*)d_in[8];
  const float* wo = (const float*)d_in[9];
  const float* bo = (const float*)d_in[10];

  const size_t NX = (size_t)MROWS * DM;  // 4M elems
  const size_t NW = (size_t)DM * DM;     // 1M elems
  hbf* base = (hbf*)d_ws;
  hbf* Xqh = base;
  hbf* Xkh = Xqh + NX;
  hbf* Xvh = Xkh + NX;
  hbf* Wqh = Xvh + NX;
  hbf* Wkh = Wqh + NW;
  hbf* Wvh = Wkh + NW;
  hbf* Woh = Wvh + NW;
  hbf* Qh  = Woh + NW;
  hbf* Kf  = Qh + NX;
  hbf* Vf  = Kf + NX;
  hbf* AOh = Vf + NX;

  cvt3w<<<dim3(1024, 4), 256, 0, stream>>>(q, k, v, Xqh, Xkh, Xvh,
                                           wq, wk, wv, wo, Wqh, Wkh, Wvh, Woh);
  gemm_qkv<<<768, 256, 0, stream>>>(Xqh, Xkh, Xvh, Wqh, Wkh, Wvh, bq, bk, bv, Qh, Kf, Vf);
  flash_attn<<<1024, 256, 0, stream>>>(Qh, Kf, Vf, AOh);
  gemm_out<<<512, 256, 0, stream>>>(AOh, Woh, bo, (float*)d_out);
}